// Round 16
// baseline (48.037 us; speedup 1.0000x reference)
//
#include <hip/hip_runtime.h>

#define DIM 64
#define HID 512
#define BATCH 8192
#define MB 32      // samples per block
#define NTHR 1024  // 16 waves

typedef __attribute__((ext_vector_type(8))) short short8;
typedef __attribute__((ext_vector_type(4))) float f32x4;
typedef __attribute__((ext_vector_type(16))) float f32x16;
typedef float float4_ __attribute__((ext_vector_type(4)));
typedef unsigned long long ull;

#define Z16 {0.f,0.f,0.f,0.f,0.f,0.f,0.f,0.f,0.f,0.f,0.f,0.f,0.f,0.f,0.f,0.f}

union U8 { short8 s8; unsigned short u[8]; };
union U4 { ull v; unsigned short u[4]; };
union FB { unsigned u; float f; };

__device__ __forceinline__ unsigned short f2bf(float f) {
    union { float f; unsigned u; } v; v.f = f;
    return (unsigned short)((v.u + 0x7FFFu + ((v.u >> 16) & 1u)) >> 16);
}
__device__ __forceinline__ float bf2f(unsigned short b) {
    FB v; v.u = (unsigned)b << 16; return v.f;
}
__device__ __forceinline__ float tanh_fast(float x) {
    float e = __expf(2.f * x);
    return 1.f - __fdividef(2.f, e + 1.f);
}

// Packs W2, P, W3, W1 into bf16 MFMA fragments + c1 = b1 + t*W1[64,:].
__global__ __launch_bounds__(256) void prep(
        const float* __restrict__ t,  const float* __restrict__ W1,
        const float* __restrict__ b1, const float* __restrict__ W2,
        const float* __restrict__ W3,
        unsigned short* __restrict__ w2pk, unsigned short* __restrict__ ppk,
        unsigned short* __restrict__ w3pk, unsigned short* __restrict__ w1pk,
        float* __restrict__ c1) {
    __shared__ float w3sT[DIM * 33];     // 32-col W3^T slice, padded
    __shared__ float w1s[DIM * DIM];     // 64-col W1 slice
    int b = blockIdx.x;
    if (b >= 288) {   // c1 tail
        int n = (b - 288) * 256 + threadIdx.x;
        c1[n] = fmaf(t[0], W1[DIM * HID + n], b1[n]);
        return;
    }
    int gid = b * 256 + threadIdx.x;
    int f = gid >> 6, l = gid & 63;
    if (f < 512) {            // W2 frags
        int nt = f >> 5, ks = f & 31;
        int n = nt * 32 + (l & 31), k0 = ks * 16 + (l >> 5) * 8;
        unsigned short* o = w2pk + (size_t)(f * 64 + l) * 8;
#pragma unroll
        for (int e = 0; e < 8; ++e) o[e] = f2bf(W2[(size_t)(k0 + e) * HID + n]);
    } else if (f < 1024) {    // P[j][n] = W2[j][n] * sum_i W1[i][j]*W3[n][i]
        int ntb = (b * 4 - 512) >> 5;            // block-uniform n-tile
        int jb  = (((b - 128) * 4) & 31) * 16;   // block-uniform 64-col W1 window
        for (int idx = threadIdx.x; idx < 32 * DIM; idx += 256) {
            int dn = idx >> 6, i = idx & 63;
            w3sT[i * 33 + dn] = W3[(size_t)(ntb * 32 + dn) * DIM + i];
        }
        for (int idx = threadIdx.x; idx < DIM * DIM; idx += 256) {
            int i = idx >> 6, jj = idx & 63;
            w1s[i * DIM + jj] = W1[(size_t)i * HID + jb + jj];
        }
        __syncthreads();
        int fi = f - 512;
        int ks = fi & 31;
        int dn = l & 31, k0 = ks * 16 + (l >> 5) * 8;   // j = k0+e (contraction)
        int n = ntb * 32 + dn;
        int jo = k0 - jb;
        float m[8] = {0.f,0.f,0.f,0.f,0.f,0.f,0.f,0.f};
#pragma unroll
        for (int i = 0; i < DIM; ++i) {
            float w3 = w3sT[i * 33 + dn];
            const float* wrow = &w1s[i * DIM + jo];
#pragma unroll
            for (int e = 0; e < 8; ++e) m[e] = fmaf(wrow[e], w3, m[e]);
        }
        unsigned short* o = ppk + (size_t)(fi * 64 + l) * 8;
#pragma unroll
        for (int e = 0; e < 8; ++e) o[e] = f2bf(W2[(size_t)(k0 + e) * HID + n] * m[e]);
    } else if (f < 1088) {    // W3 frags (N=64): fi = nt*16 + ks
        int fi = f - 1024;
        int nt = fi >> 4, ks = fi & 15;
        int n = nt * 16 + (l & 15), k0 = ks * 32 + (l >> 4) * 8;
        unsigned short* o = w3pk + (size_t)(fi * 64 + l) * 8;
#pragma unroll
        for (int e = 0; e < 8; ++e) o[e] = f2bf(W3[(size_t)(k0 + e) * DIM + n]);
    } else {                  // W1 A-frags: fi = mt*2 + ks
        int fi = f - 1088;
        int nt = fi >> 1, ks = fi & 1;
        int n = nt * 16 + (l & 15), k0 = ks * 32 + (l >> 4) * 8;
        unsigned short* o = w1pk + (size_t)(fi * 64 + l) * 8;
#pragma unroll
        for (int e = 0; e < 8; ++e) o[e] = f2bf(W1[(size_t)(k0 + e) * HID + n]);
    }
}

// LDS activation tiles: [sample][col] bf16, pitch 1024B, byte ^= (sample&15)<<4
__device__ __forceinline__ int act_addr(int sample, int colbyte) {
    return (sample * 1024 + colbyte) ^ ((sample & 15) << 4);
}

// phase-1 helper body (h-or-d select at compile time via STORE_D)
template <int STORE_D>
__device__ __forceinline__ void phase1(
        const float* __restrict__ x, const float* __restrict__ c1,
        const unsigned short* __restrict__ w1pk,
        char* dstb, int s0, int w, int l) {
    const int lr = l & 15, g = l >> 4;
    short8 xf[2][2];
#pragma unroll
    for (int nt = 0; nt < 2; ++nt)
#pragma unroll
        for (int ks = 0; ks < 2; ++ks) {
            const float* xp = x + (size_t)(s0 + nt * 16 + lr) * DIM + ks * 32 + g * 8;
            float4_ x0 = *(const float4_*)xp;
            float4_ x1 = *(const float4_*)(xp + 4);
            U8 u;
            u.u[0]=f2bf(x0.x); u.u[1]=f2bf(x0.y); u.u[2]=f2bf(x0.z); u.u[3]=f2bf(x0.w);
            u.u[4]=f2bf(x1.x); u.u[5]=f2bf(x1.y); u.u[6]=f2bf(x1.z); u.u[7]=f2bf(x1.w);
            xf[nt][ks] = u.s8;
        }
#pragma unroll
    for (int mi = 0; mi < 2; ++mi) {
        int mt = w * 2 + mi;
        short8 a0 = ((const short8*)w1pk)[(size_t)((mt * 2 + 0) * 64 + l)];
        short8 a1 = ((const short8*)w1pk)[(size_t)((mt * 2 + 1) * 64 + l)];
        float c1q[4];
#pragma unroll
        for (int r = 0; r < 4; ++r) c1q[r] = c1[mt * 16 + g * 4 + r];
#pragma unroll
        for (int nt = 0; nt < 2; ++nt) {
            f32x4 acc = {0.f, 0.f, 0.f, 0.f};
            acc = __builtin_amdgcn_mfma_f32_16x16x32_bf16(a0, xf[nt][0], acc, 0, 0, 0);
            acc = __builtin_amdgcn_mfma_f32_16x16x32_bf16(a1, xf[nt][1], acc, 0, 0, 0);
            int sample = nt * 16 + lr;
            U4 u;
#pragma unroll
            for (int r = 0; r < 4; ++r) {
                float h = tanh_fast(acc[r] + c1q[r]);
                u.u[r] = STORE_D ? f2bf(fmaf(-h, h, 1.f)) : f2bf(h);
            }
            *(ull*)(dstb + act_addr(sample, (mt * 16 + g * 4) * 2)) = u.v;
        }
    }
}

// zmain: h1 -> z2 = h1@W2+b2 -> h2 (LDS + global image) -> v = h2@W3+b3
__global__ __launch_bounds__(NTHR, 4) void zmain(
        const float* __restrict__ x,  const float* __restrict__ c1,
        const float* __restrict__ b2, const float* __restrict__ b3,
        const unsigned short* __restrict__ w1pk, const unsigned short* __restrict__ w2pk,
        const unsigned short* __restrict__ w3pk,
        unsigned short* __restrict__ h2img, float* __restrict__ out) {
    __shared__ unsigned short h1s[MB * HID];   // 32 KB
    __shared__ unsigned short h2s[MB * HID];   // 32 KB
    char* h1b = (char*)h1s; char* h2b = (char*)h2s;
    const int tid = threadIdx.x, w = tid >> 6, l = tid & 63;
    const int lr = l & 15, g = l >> 4;
    const int s0 = blockIdx.x * MB;

    phase1<0>(x, c1, w1pk, h1b, s0, w, l);
    __syncthreads();

    // z-GEMM: wave w owns n-tile w (32 cols); one acc, one B-stream
    const short8* bwp = (const short8*)w2pk + (size_t)(w * 32) * 64 + l;
    f32x16 z = Z16;
#pragma unroll 4
    for (int ks = 0; ks < 32; ++ks) {
        short8 av = *(const short8*)(h1b + act_addr(l & 31, ks * 32 + (l >> 5) * 16));
        z = __builtin_amdgcn_mfma_f32_32x32x16_bf16(av, bwp[ks * 64], z, 0, 0, 0);
    }
    {
        int c = w * 32 + (l & 31);
        float b2v = b2[c];
#pragma unroll
        for (int r = 0; r < 16; ++r) {
            int row = (r & 3) + 8 * (r >> 2) + 4 * (l >> 5);
            *(unsigned short*)(h2b + act_addr(row, c * 2)) = f2bf(tanh_fast(z[r] + b2v));
        }
    }
    __syncthreads();   // h2s complete

    if (w < 8) {
        // phase 3: v = h2 @ W3 + b3
        const int wm3 = w & 1, wn3 = w >> 1;
        f32x4 acc = {0.f, 0.f, 0.f, 0.f};
        const short8* W3f = (const short8*)w3pk + (size_t)(wn3 * 16) * 64 + l;
#pragma unroll
        for (int ks = 0; ks < 16; ++ks) {
            short8 ah = *(const short8*)(h2b + act_addr(wm3 * 16 + lr, ks * 64 + g * 16));
            acc = __builtin_amdgcn_mfma_f32_16x16x32_bf16(ah, W3f[ks * 64], acc, 0, 0, 0);
        }
        int c = wn3 * 16 + lr;
        float b3v = b3[c];
#pragma unroll
        for (int r = 0; r < 4; ++r)
            out[(size_t)(s0 + wm3 * 16 + g * 4 + r) * DIM + c] = acc[r] + b3v;
    } else {
        // bulk-copy h2 LDS image -> global (coalesced b128)
        int tsrc = tid - 512;
        float4_* dst = (float4_*)(h2img + (size_t)blockIdx.x * MB * HID);
        const float4_* s4 = (const float4_*)h2s;
#pragma unroll
        for (int k = 0; k < 4; ++k) dst[tsrc * 4 + k] = s4[tsrc * 4 + k];
    }
}

// smain: d1 -> srow = d1@P -> div = -sum srow*(1-h2^2)
__global__ __launch_bounds__(NTHR, 4) void smain(
        const float* __restrict__ x,  const float* __restrict__ c1,
        const unsigned short* __restrict__ w1pk, const unsigned short* __restrict__ ppk,
        const unsigned short* __restrict__ h2img, float* __restrict__ out) {
    __shared__ unsigned short d1s[MB * HID];   // 32 KB
    __shared__ unsigned short h2l[MB * HID];   // 32 KB
    __shared__ float wred[16][MB];
    char* d1b = (char*)d1s; char* h2b = (char*)h2l;
    const int tid = threadIdx.x, w = tid >> 6, l = tid & 63;
    const int s0 = blockIdx.x * MB;

    phase1<1>(x, c1, w1pk, d1b, s0, w, l);
    // issue h2 image loads now; consumed after the GEMM (latency hidden)
    const float4_* src = (const float4_*)(h2img + (size_t)blockIdx.x * MB * HID);
    float4_ hv0 = src[tid * 2 + 0];
    float4_ hv1 = src[tid * 2 + 1];
    __syncthreads();

    // s-GEMM: wave w owns n-tile w
    const short8* bpp = (const short8*)ppk + (size_t)(w * 32) * 64 + l;
    f32x16 s = Z16;
#pragma unroll 4
    for (int ks = 0; ks < 32; ++ks) {
        short8 av = *(const short8*)(d1b + act_addr(l & 31, ks * 32 + (l >> 5) * 16));
        s = __builtin_amdgcn_mfma_f32_32x32x16_bf16(av, bpp[ks * 64], s, 0, 0, 0);
    }
    ((float4_*)h2l)[tid * 2 + 0] = hv0;
    ((float4_*)h2l)[tid * 2 + 1] = hv1;
    __syncthreads();   // h2l ready

    float divp[16];
    {
        int c = w * 32 + (l & 31);
#pragma unroll
        for (int r = 0; r < 16; ++r) {
            int row = (r & 3) + 8 * (r >> 2) + 4 * (l >> 5);
            float h2 = bf2f(*(const unsigned short*)(h2b + act_addr(row, c * 2)));
            divp[r] = s[r] * fmaf(-h2, h2, 1.f);
        }
    }
#pragma unroll
    for (int off = 1; off < 32; off <<= 1) {
#pragma unroll
        for (int r = 0; r < 16; ++r) divp[r] += __shfl_xor(divp[r], off, 64);
    }
    if ((l & 31) == 0) {
#pragma unroll
        for (int r = 0; r < 16; ++r) {
            int row = (r & 3) + 8 * (r >> 2) + 4 * (l >> 5);
            wred[w][row] = divp[r];
        }
    }
    __syncthreads();
    if (tid < MB) {
        float d = 0.f;
#pragma unroll
        for (int ww = 0; ww < 16; ++ww) d += wred[ww][tid];
        out[(size_t)BATCH * DIM + s0 + tid] = -d;
    }
}

extern "C" void kernel_launch(void* const* d_in, const int* in_sizes, int n_in,
                              void* d_out, int out_size, void* d_ws, size_t ws_size,
                              hipStream_t stream) {
    const float* t  = (const float*)d_in[0];
    const float* x  = (const float*)d_in[1];
    const float* W1 = (const float*)d_in[2];
    const float* b1 = (const float*)d_in[3];
    const float* W2 = (const float*)d_in[4];
    const float* b2 = (const float*)d_in[5];
    const float* W3 = (const float*)d_in[6];
    const float* b3 = (const float*)d_in[7];
    float* out = (float*)d_out;

    char* ws = (char*)d_ws;
    unsigned short* w2pk  = (unsigned short*)ws;                             // 512 KB
    unsigned short* ppk   = (unsigned short*)(ws + (512 << 10));             // 512 KB
    unsigned short* w3pk  = (unsigned short*)(ws + (1 << 20));               // 64 KB
    unsigned short* w1pk  = (unsigned short*)(ws + (1 << 20) + (64 << 10));  // 64 KB
    float*          c1    = (float*)(ws + (1 << 20) + (128 << 10));          // 2 KB
    unsigned short* h2img = (unsigned short*)(ws + (1 << 20) + (192 << 10)); // 8 MB

    prep <<<290, 256, 0, stream>>>(t, W1, b1, W2, W3, w2pk, ppk, w3pk, w1pk, c1);
    zmain<<<BATCH / MB, NTHR, 0, stream>>>(x, c1, b2, b3, w1pk, w2pk, w3pk, h2img, out);
    smain<<<BATCH / MB, NTHR, 0, stream>>>(x, c1, w1pk, ppk, h2img, out);
}

// Round 17
// 33.892 us; speedup vs baseline: 1.4174x; 1.4174x over previous
//
#include <hip/hip_runtime.h>

#define DIM 64
#define HID 512
#define BATCH 8192
#define MB 32      // samples per block
#define NTHR 1024  // 16 waves: 8 z-waves + 8 s-waves

typedef __attribute__((ext_vector_type(8))) short short8;
typedef __attribute__((ext_vector_type(4))) float f32x4;
typedef __attribute__((ext_vector_type(16))) float f32x16;
typedef float float4_ __attribute__((ext_vector_type(4)));
typedef unsigned long long ull;

#define Z16 {0.f,0.f,0.f,0.f,0.f,0.f,0.f,0.f,0.f,0.f,0.f,0.f,0.f,0.f,0.f,0.f}

union U8 { short8 s8; unsigned short u[8]; };
union U4 { ull v; unsigned short u[4]; };
union FB { unsigned u; float f; };

__device__ __forceinline__ unsigned short f2bf(float f) {
    union { float f; unsigned u; } v; v.f = f;
    return (unsigned short)((v.u + 0x7FFFu + ((v.u >> 16) & 1u)) >> 16);
}
__device__ __forceinline__ float bf2f(unsigned short b) {
    FB v; v.u = (unsigned)b << 16; return v.f;
}
__device__ __forceinline__ float tanh_fast(float x) {
    float e = __expf(2.f * x);
    return 1.f - __fdividef(2.f, e + 1.f);
}

// Packs W2, P, W3, W1 into bf16 MFMA fragments + c1 = b1 + t*W1[64,:].
// P-branch: W1 slice + W3^T slice staged in LDS (latency fix, R13).
__global__ __launch_bounds__(256) void prep(
        const float* __restrict__ t,  const float* __restrict__ W1,
        const float* __restrict__ b1, const float* __restrict__ W2,
        const float* __restrict__ W3,
        unsigned short* __restrict__ w2pk, unsigned short* __restrict__ ppk,
        unsigned short* __restrict__ w3pk, unsigned short* __restrict__ w1pk,
        float* __restrict__ c1) {
    __shared__ float w3sT[DIM * 33];     // 32-col W3^T slice, padded
    __shared__ float w1s[DIM * DIM];     // 64-col W1 slice
    int b = blockIdx.x;
    if (b >= 288) {   // c1 tail
        int n = (b - 288) * 256 + threadIdx.x;
        c1[n] = fmaf(t[0], W1[DIM * HID + n], b1[n]);
        return;
    }
    int gid = b * 256 + threadIdx.x;
    int f = gid >> 6, l = gid & 63;
    if (f < 512) {            // W2 frags
        int nt = f >> 5, ks = f & 31;
        int n = nt * 32 + (l & 31), k0 = ks * 16 + (l >> 5) * 8;
        unsigned short* o = w2pk + (size_t)(f * 64 + l) * 8;
#pragma unroll
        for (int e = 0; e < 8; ++e) o[e] = f2bf(W2[(size_t)(k0 + e) * HID + n]);
    } else if (f < 1024) {    // P[j][n] = W2[j][n] * sum_i W1[i][j]*W3[n][i]
        int ntb = (b * 4 - 512) >> 5;            // block-uniform n-tile
        int jb  = (((b - 128) * 4) & 31) * 16;   // block-uniform 64-col W1 window
        for (int idx = threadIdx.x; idx < 32 * DIM; idx += 256) {
            int dn = idx >> 6, i = idx & 63;
            w3sT[i * 33 + dn] = W3[(size_t)(ntb * 32 + dn) * DIM + i];
        }
        for (int idx = threadIdx.x; idx < DIM * DIM; idx += 256) {
            int i = idx >> 6, jj = idx & 63;
            w1s[i * DIM + jj] = W1[(size_t)i * HID + jb + jj];
        }
        __syncthreads();
        int fi = f - 512;
        int ks = fi & 31;
        int dn = l & 31, k0 = ks * 16 + (l >> 5) * 8;   // j = k0+e (contraction)
        int n = ntb * 32 + dn;
        int jo = k0 - jb;
        float m[8] = {0.f,0.f,0.f,0.f,0.f,0.f,0.f,0.f};
#pragma unroll
        for (int i = 0; i < DIM; ++i) {
            float w3 = w3sT[i * 33 + dn];
            const float* wrow = &w1s[i * DIM + jo];
#pragma unroll
            for (int e = 0; e < 8; ++e) m[e] = fmaf(wrow[e], w3, m[e]);
        }
        unsigned short* o = ppk + (size_t)(fi * 64 + l) * 8;
#pragma unroll
        for (int e = 0; e < 8; ++e) o[e] = f2bf(W2[(size_t)(k0 + e) * HID + n] * m[e]);
    } else if (f < 1088) {    // W3 frags (N=64): fi = nt*16 + ks
        int fi = f - 1024;
        int nt = fi >> 4, ks = fi & 15;
        int n = nt * 16 + (l & 15), k0 = ks * 32 + (l >> 4) * 8;
        unsigned short* o = w3pk + (size_t)(fi * 64 + l) * 8;
#pragma unroll
        for (int e = 0; e < 8; ++e) o[e] = f2bf(W3[(size_t)(k0 + e) * DIM + n]);
    } else {                  // W1 A-frags: fi = mt*2 + ks
        int fi = f - 1088;
        int nt = fi >> 1, ks = fi & 1;
        int n = nt * 16 + (l & 15), k0 = ks * 32 + (l >> 4) * 8;
        unsigned short* o = w1pk + (size_t)(fi * 64 + l) * 8;
#pragma unroll
        for (int e = 0; e < 8; ++e) o[e] = f2bf(W1[(size_t)(k0 + e) * HID + n]);
    }
}

// LDS activation tiles: [sample][col] bf16, pitch 1024B, byte ^= (sample&15)<<4
__device__ __forceinline__ int act_addr(int sample, int colbyte) {
    return (sample * 1024 + colbyte) ^ ((sample & 15) << 4);
}

__global__ __launch_bounds__(NTHR) void fused_main(
        const float* __restrict__ x,  const float* __restrict__ c1,
        const float* __restrict__ b2, const float* __restrict__ b3,
        const unsigned short* __restrict__ w1pk, const unsigned short* __restrict__ w2pk,
        const unsigned short* __restrict__ ppk,  const unsigned short* __restrict__ w3pk,
        float* __restrict__ out) {
    __shared__ unsigned short h1s[MB * HID];   // 32 KB
    __shared__ unsigned short d1s[MB * HID];   // 32 KB
    __shared__ unsigned short h2s[MB * HID];   // 32 KB
    __shared__ float sdump[8 * 16 * 64];       // 32 KB: s-wave q's first acc, [q*16+r][l]
    __shared__ float wred[8][MB];
    char* h1b = (char*)h1s; char* d1b = (char*)d1s; char* h2b = (char*)h2s;

    const int tid = threadIdx.x, w = tid >> 6, l = tid & 63;
    const int lr = l & 15, g = l >> 4;
    const int s0 = blockIdx.x * MB;

    // ======== phase 1^T (16x16): h1^T = tanh(W1^T x^T + c1) ; 16 waves, 2 hid-tiles each ===
    short8 xf[2][2];
#pragma unroll
    for (int nt = 0; nt < 2; ++nt)
#pragma unroll
        for (int ks = 0; ks < 2; ++ks) {
            const float* xp = x + (size_t)(s0 + nt * 16 + lr) * DIM + ks * 32 + g * 8;
            float4_ x0 = *(const float4_*)xp;
            float4_ x1 = *(const float4_*)(xp + 4);
            U8 u;
            u.u[0]=f2bf(x0.x); u.u[1]=f2bf(x0.y); u.u[2]=f2bf(x0.z); u.u[3]=f2bf(x0.w);
            u.u[4]=f2bf(x1.x); u.u[5]=f2bf(x1.y); u.u[6]=f2bf(x1.z); u.u[7]=f2bf(x1.w);
            xf[nt][ks] = u.s8;
        }
#pragma unroll
    for (int mi = 0; mi < 2; ++mi) {
        int mt = w * 2 + mi;
        short8 a0 = ((const short8*)w1pk)[(size_t)((mt * 2 + 0) * 64 + l)];
        short8 a1 = ((const short8*)w1pk)[(size_t)((mt * 2 + 1) * 64 + l)];
        float c1q[4];
#pragma unroll
        for (int r = 0; r < 4; ++r) c1q[r] = c1[mt * 16 + g * 4 + r];
#pragma unroll
        for (int nt = 0; nt < 2; ++nt) {
            f32x4 acc = {0.f, 0.f, 0.f, 0.f};
            acc = __builtin_amdgcn_mfma_f32_16x16x32_bf16(a0, xf[nt][0], acc, 0, 0, 0);
            acc = __builtin_amdgcn_mfma_f32_16x16x32_bf16(a1, xf[nt][1], acc, 0, 0, 0);
            int sample = nt * 16 + lr;
            U4 hu, du;
#pragma unroll
            for (int r = 0; r < 4; ++r) {
                float h = tanh_fast(acc[r] + c1q[r]);
                hu.u[r] = f2bf(h);
                du.u[r] = f2bf(fmaf(-h, h, 1.f));
            }
            int ab = act_addr(sample, (mt * 16 + g * 4) * 2);
            *(ull*)(h1b + ab) = hu.v;
            *(ull*)(d1b + ab) = du.v;
        }
    }
    __syncthreads();

    // ======== phase 2 (32x32x16) ROLE-SPLIT, SEQUENTIAL n-tiles: ONE acc live at a time ====
    // z-waves (w<8): h1@W2 -> h2 per tile.  s-waves (w>=8): d1@P; acc0 -> sdump, acc1 in regs.
    const int q = w & 7, role = w >> 3;
    const short8* Bbase = (const short8*)(role ? ppk : w2pk);
    const char* Ab = role ? d1b : h1b;
    f32x16 s1 = Z16;   // s-wave's second acc (z-waves leave unused)

#pragma unroll
    for (int j = 0; j < 2; ++j) {
        const int nt = 2 * q + j;
        const short8* bs = Bbase + (size_t)(nt * 32) * 64 + l;
        f32x16 acc = Z16;
#pragma unroll 2
        for (int ks = 0; ks < 32; ++ks) {
            short8 av = *(const short8*)(Ab + act_addr(l & 31, ks * 32 + (l >> 5) * 16));
            acc = __builtin_amdgcn_mfma_f32_32x32x16_bf16(av, bs[ks * 64], acc, 0, 0, 0);
        }
        if (role == 0) {
            int c = nt * 32 + (l & 31);
            float b2v = b2[c];
#pragma unroll
            for (int r = 0; r < 16; ++r) {
                int row = (r & 3) + 8 * (r >> 2) + 4 * (l >> 5);
                *(unsigned short*)(h2b + act_addr(row, c * 2)) = f2bf(tanh_fast(acc[r] + b2v));
            }
        } else if (j == 0) {
#pragma unroll
            for (int r = 0; r < 16; ++r) sdump[(q * 16 + r) * 64 + l] = acc[r];
        } else {
            s1 = acc;
        }
    }
    __syncthreads();   // h2s + sdump complete

    if (role == 1) {
        // div partials over both owned n-tiles; overlaps with z-waves' phase 3
        float divp[16];
        int c0 = (2 * q) * 32 + (l & 31), c1c = c0 + 32;
#pragma unroll
        for (int r = 0; r < 16; ++r) {
            int row = (r & 3) + 8 * (r >> 2) + 4 * (l >> 5);
            float h2a = bf2f(*(const unsigned short*)(h2b + act_addr(row, c0 * 2)));
            float h2c = bf2f(*(const unsigned short*)(h2b + act_addr(row, c1c * 2)));
            float s0v = sdump[(q * 16 + r) * 64 + l];
            divp[r] = s0v * fmaf(-h2a, h2a, 1.f) + s1[r] * fmaf(-h2c, h2c, 1.f);
        }
#pragma unroll
        for (int off = 1; off < 32; off <<= 1) {
#pragma unroll
            for (int r = 0; r < 16; ++r) divp[r] += __shfl_xor(divp[r], off, 64);
        }
        if ((l & 31) == 0) {
#pragma unroll
            for (int r = 0; r < 16; ++r) {
                int row = (r & 3) + 8 * (r >> 2) + 4 * (l >> 5);
                wred[q][row] = divp[r];
            }
        }
    } else {
        // z-waves: phase 3 (16x16): v = h2 @ W3 + b3
        const int wm3 = w & 1, wn3 = w >> 1;
        f32x4 acc = {0.f, 0.f, 0.f, 0.f};
        const short8* W3f = (const short8*)w3pk + (size_t)(wn3 * 16) * 64 + l;
#pragma unroll
        for (int ks = 0; ks < 16; ++ks) {
            short8 ah = *(const short8*)(h2b + act_addr(wm3 * 16 + lr, ks * 64 + g * 16));
            acc = __builtin_amdgcn_mfma_f32_16x16x32_bf16(ah, W3f[ks * 64], acc, 0, 0, 0);
        }
        int c = wn3 * 16 + lr;
        float b3v = b3[c];
#pragma unroll
        for (int r = 0; r < 4; ++r)
            out[(size_t)(s0 + wm3 * 16 + g * 4 + r) * DIM + c] = acc[r] + b3v;
    }
    __syncthreads();   // wred complete
    if (tid < MB) {
        float d = 0.f;
#pragma unroll
        for (int ww = 0; ww < 8; ++ww) d += wred[ww][tid];
        out[(size_t)BATCH * DIM + s0 + tid] = -d;
    }
}

extern "C" void kernel_launch(void* const* d_in, const int* in_sizes, int n_in,
                              void* d_out, int out_size, void* d_ws, size_t ws_size,
                              hipStream_t stream) {
    const float* t  = (const float*)d_in[0];
    const float* x  = (const float*)d_in[1];
    const float* W1 = (const float*)d_in[2];
    const float* b1 = (const float*)d_in[3];
    const float* W2 = (const float*)d_in[4];
    const float* b2 = (const float*)d_in[5];
    const float* W3 = (const float*)d_in[6];
    const float* b3 = (const float*)d_in[7];
    float* out = (float*)d_out;

    char* ws = (char*)d_ws;
    unsigned short* w2pk = (unsigned short*)ws;                            // 512 KB
    unsigned short* ppk  = (unsigned short*)(ws + (512 << 10));            // 512 KB
    unsigned short* w3pk = (unsigned short*)(ws + (1 << 20));              // 64 KB
    unsigned short* w1pk = (unsigned short*)(ws + (1 << 20) + (64 << 10)); // 64 KB
    float*          c1   = (float*)(ws + (1 << 20) + (128 << 10));         // 2 KB

    prep<<<290, 256, 0, stream>>>(t, W1, b1, W2, W3, w2pk, ppk, w3pk, w1pk, c1);
    fused_main<<<BATCH / MB, NTHR, 0, stream>>>(x, c1, b2, b3, w1pk, w2pk, ppk, w3pk, out);
}

// Round 18
// 32.703 us; speedup vs baseline: 1.4689x; 1.0363x over previous
//
#include <hip/hip_runtime.h>

#define DIM 64
#define HID 512
#define BATCH 8192
#define MB 32      // samples per block
#define NTHR 1024  // 16 waves: 8 z-waves + 8 s-waves

typedef __attribute__((ext_vector_type(8))) short short8;
typedef __attribute__((ext_vector_type(4))) float f32x4;
typedef __attribute__((ext_vector_type(16))) float f32x16;
typedef float float4_ __attribute__((ext_vector_type(4)));
typedef unsigned long long ull;

#define Z16 {0.f,0.f,0.f,0.f,0.f,0.f,0.f,0.f,0.f,0.f,0.f,0.f,0.f,0.f,0.f,0.f}

union U8 { short8 s8; unsigned short u[8]; };
union U4 { ull v; unsigned short u[4]; };
union FB { unsigned u; float f; };

__device__ __forceinline__ unsigned short f2bf(float f) {
    union { float f; unsigned u; } v; v.f = f;
    return (unsigned short)((v.u + 0x7FFFu + ((v.u >> 16) & 1u)) >> 16);
}
__device__ __forceinline__ float bf2f(unsigned short b) {
    FB v; v.u = (unsigned)b << 16; return v.f;
}
__device__ __forceinline__ float tanh_fast(float x) {
    float e = __expf(2.f * x);
    return 1.f - __fdividef(2.f, e + 1.f);
}

// Packs W2, P, W3, W1 into bf16 MFMA fragments + c1 = b1 + t*W1[64,:].
// P-branch: W1 slice + W3^T slice staged in LDS (latency fix, R13).
__global__ __launch_bounds__(256) void prep(
        const float* __restrict__ t,  const float* __restrict__ W1,
        const float* __restrict__ b1, const float* __restrict__ W2,
        const float* __restrict__ W3,
        unsigned short* __restrict__ w2pk, unsigned short* __restrict__ ppk,
        unsigned short* __restrict__ w3pk, unsigned short* __restrict__ w1pk,
        float* __restrict__ c1) {
    __shared__ float w3sT[DIM * 33];     // 32-col W3^T slice, padded
    __shared__ float w1s[DIM * DIM];     // 64-col W1 slice
    int b = blockIdx.x;
    if (b >= 288) {   // c1 tail
        int n = (b - 288) * 256 + threadIdx.x;
        c1[n] = fmaf(t[0], W1[DIM * HID + n], b1[n]);
        return;
    }
    int gid = b * 256 + threadIdx.x;
    int f = gid >> 6, l = gid & 63;
    if (f < 512) {            // W2 frags
        int nt = f >> 5, ks = f & 31;
        int n = nt * 32 + (l & 31), k0 = ks * 16 + (l >> 5) * 8;
        unsigned short* o = w2pk + (size_t)(f * 64 + l) * 8;
#pragma unroll
        for (int e = 0; e < 8; ++e) o[e] = f2bf(W2[(size_t)(k0 + e) * HID + n]);
    } else if (f < 1024) {    // P[j][n] = W2[j][n] * sum_i W1[i][j]*W3[n][i]
        int ntb = (b * 4 - 512) >> 5;            // block-uniform n-tile
        int jb  = (((b - 128) * 4) & 31) * 16;   // block-uniform 64-col W1 window
        for (int idx = threadIdx.x; idx < 32 * DIM; idx += 256) {
            int dn = idx >> 6, i = idx & 63;
            w3sT[i * 33 + dn] = W3[(size_t)(ntb * 32 + dn) * DIM + i];
        }
        for (int idx = threadIdx.x; idx < DIM * DIM; idx += 256) {
            int i = idx >> 6, jj = idx & 63;
            w1s[i * DIM + jj] = W1[(size_t)i * HID + jb + jj];
        }
        __syncthreads();
        int fi = f - 512;
        int ks = fi & 31;
        int dn = l & 31, k0 = ks * 16 + (l >> 5) * 8;   // j = k0+e (contraction)
        int n = ntb * 32 + dn;
        int jo = k0 - jb;
        float m[8] = {0.f,0.f,0.f,0.f,0.f,0.f,0.f,0.f};
#pragma unroll
        for (int i = 0; i < DIM; ++i) {
            float w3 = w3sT[i * 33 + dn];
            const float* wrow = &w1s[i * DIM + jo];
#pragma unroll
            for (int e = 0; e < 8; ++e) m[e] = fmaf(wrow[e], w3, m[e]);
        }
        unsigned short* o = ppk + (size_t)(fi * 64 + l) * 8;
#pragma unroll
        for (int e = 0; e < 8; ++e) o[e] = f2bf(W2[(size_t)(k0 + e) * HID + n] * m[e]);
    } else if (f < 1088) {    // W3 frags (N=64): fi = nt*16 + ks
        int fi = f - 1024;
        int nt = fi >> 4, ks = fi & 15;
        int n = nt * 16 + (l & 15), k0 = ks * 32 + (l >> 4) * 8;
        unsigned short* o = w3pk + (size_t)(fi * 64 + l) * 8;
#pragma unroll
        for (int e = 0; e < 8; ++e) o[e] = f2bf(W3[(size_t)(k0 + e) * DIM + n]);
    } else {                  // W1 A-frags: fi = mt*2 + ks
        int fi = f - 1088;
        int nt = fi >> 1, ks = fi & 1;
        int n = nt * 16 + (l & 15), k0 = ks * 32 + (l >> 4) * 8;
        unsigned short* o = w1pk + (size_t)(fi * 64 + l) * 8;
#pragma unroll
        for (int e = 0; e < 8; ++e) o[e] = f2bf(W1[(size_t)(k0 + e) * HID + n]);
    }
}

// LDS activation tiles: [sample][col] bf16, pitch 1024B, byte ^= (sample&15)<<4
__device__ __forceinline__ int act_addr(int sample, int colbyte) {
    return (sample * 1024 + colbyte) ^ ((sample & 15) << 4);
}

__global__ __launch_bounds__(NTHR)
__attribute__((amdgpu_waves_per_eu(4, 4)))
void fused_main(
        const float* __restrict__ x,  const float* __restrict__ c1,
        const float* __restrict__ b2, const float* __restrict__ b3,
        const unsigned short* __restrict__ w1pk, const unsigned short* __restrict__ w2pk,
        const unsigned short* __restrict__ ppk,  const unsigned short* __restrict__ w3pk,
        float* __restrict__ out) {
    __shared__ unsigned short h1s[MB * HID];   // 32 KB
    __shared__ unsigned short d1s[MB * HID];   // 32 KB
    __shared__ unsigned short h2s[MB * HID];   // 32 KB
    __shared__ float wred[8][MB];
    char* h1b = (char*)h1s; char* d1b = (char*)d1s; char* h2b = (char*)h2s;

    const int tid = threadIdx.x, w = tid >> 6, l = tid & 63;
    const int lr = l & 15, g = l >> 4;
    const int bid = blockIdx.x;
    const int s0 = bid * MB;

    // ======== phase 1^T (16x16): h1^T = tanh(W1^T x^T + c1) ; 16 waves, 2 hid-tiles each ===
    short8 xf[2][2];
#pragma unroll
    for (int nt = 0; nt < 2; ++nt)
#pragma unroll
        for (int ks = 0; ks < 2; ++ks) {
            const float* xp = x + (size_t)(s0 + nt * 16 + lr) * DIM + ks * 32 + g * 8;
            float4_ x0 = *(const float4_*)xp;
            float4_ x1 = *(const float4_*)(xp + 4);
            U8 u;
            u.u[0]=f2bf(x0.x); u.u[1]=f2bf(x0.y); u.u[2]=f2bf(x0.z); u.u[3]=f2bf(x0.w);
            u.u[4]=f2bf(x1.x); u.u[5]=f2bf(x1.y); u.u[6]=f2bf(x1.z); u.u[7]=f2bf(x1.w);
            xf[nt][ks] = u.s8;
        }
#pragma unroll
    for (int mi = 0; mi < 2; ++mi) {
        int mt = w * 2 + mi;
        short8 a0 = ((const short8*)w1pk)[(size_t)((mt * 2 + 0) * 64 + l)];
        short8 a1 = ((const short8*)w1pk)[(size_t)((mt * 2 + 1) * 64 + l)];
        float c1q[4];
#pragma unroll
        for (int r = 0; r < 4; ++r) c1q[r] = c1[mt * 16 + g * 4 + r];
#pragma unroll
        for (int nt = 0; nt < 2; ++nt) {
            f32x4 acc = {0.f, 0.f, 0.f, 0.f};
            acc = __builtin_amdgcn_mfma_f32_16x16x32_bf16(a0, xf[nt][0], acc, 0, 0, 0);
            acc = __builtin_amdgcn_mfma_f32_16x16x32_bf16(a1, xf[nt][1], acc, 0, 0, 0);
            int sample = nt * 16 + lr;
            U4 hu, du;
#pragma unroll
            for (int r = 0; r < 4; ++r) {
                float h = tanh_fast(acc[r] + c1q[r]);
                hu.u[r] = f2bf(h);
                du.u[r] = f2bf(fmaf(-h, h, 1.f));
            }
            int ab = act_addr(sample, (mt * 16 + g * 4) * 2);
            *(ull*)(h1b + ab) = hu.v;
            *(ull*)(d1b + ab) = du.v;
        }
    }
    __syncthreads();

    // ======== phase 2 (32x32x16) ROLE-SPLIT + per-block address decorrelation ========
    // n-tile rotation q2 = (q+bid)&7 and ks-loop start rotation (bid*5)&31 spread the
    // 256 blocks' identical weight streams across L2 banks (anti-camping).
    const int q = w & 7, role = w >> 3;
    const int q2 = (q + bid) & 7;
    const short8* Bf = (const short8*)(role ? ppk : w2pk);
    const char* Ab = role ? d1b : h1b;
    const short8* b0p = Bf + (size_t)((2 * q2 + 0) * 32) * 64 + l;
    const short8* b1p = Bf + (size_t)((2 * q2 + 1) * 32) * 64 + l;
    const int rot = (bid * 5) & 31;
    f32x16 a0 = Z16, a1 = Z16;
#pragma unroll 4
    for (int i = 0; i < 32; ++i) {
        int ks = (i + rot) & 31;
        int ab = act_addr(l & 31, ks * 32 + (l >> 5) * 16);
        short8 av  = *(const short8*)(Ab + ab);
        short8 b0v = b0p[ks * 64];
        short8 b1v = b1p[ks * 64];
        a0 = __builtin_amdgcn_mfma_f32_32x32x16_bf16(av, b0v, a0, 0, 0, 0);
        a1 = __builtin_amdgcn_mfma_f32_32x32x16_bf16(av, b1v, a1, 0, 0, 0);
    }

    // z-waves: h2 = tanh(z + b2) -> h2s (bf16)
    if (role == 0) {
#pragma unroll
        for (int j = 0; j < 2; ++j) {
            int c = (2 * q2 + j) * 32 + (l & 31);
            float b2v = b2[c];
            f32x16 acc = j ? a1 : a0;
#pragma unroll
            for (int r = 0; r < 16; ++r) {
                int row = (r & 3) + 8 * (r >> 2) + 4 * (l >> 5);
                float h2 = tanh_fast(acc[r] + b2v);
                *(unsigned short*)(h2b + act_addr(row, c * 2)) = f2bf(h2);
            }
        }
    }
    __syncthreads();   // h2s complete

    if (role == 1) {
        // s-waves: div partials = sum_c s * (1 - h2^2); overlaps with z-waves' phase 3
        float divp[16];
#pragma unroll
        for (int r = 0; r < 16; ++r) divp[r] = 0.f;
#pragma unroll
        for (int j = 0; j < 2; ++j) {
            int c = (2 * q2 + j) * 32 + (l & 31);
            f32x16 acc = j ? a1 : a0;
#pragma unroll
            for (int r = 0; r < 16; ++r) {
                int row = (r & 3) + 8 * (r >> 2) + 4 * (l >> 5);
                float h2 = bf2f(*(const unsigned short*)(h2b + act_addr(row, c * 2)));
                divp[r] = fmaf(acc[r], fmaf(-h2, h2, 1.f), divp[r]);
            }
        }
#pragma unroll
        for (int off = 1; off < 32; off <<= 1) {
#pragma unroll
            for (int r = 0; r < 16; ++r) divp[r] += __shfl_xor(divp[r], off, 64);
        }
        if ((l & 31) == 0) {
#pragma unroll
            for (int r = 0; r < 16; ++r) {
                int row = (r & 3) + 8 * (r >> 2) + 4 * (l >> 5);
                wred[q2][row] = divp[r];
            }
        }
    } else {
        // z-waves: phase 3 (16x16): v = h2 @ W3 + b3, ks-rotated per block
        const int wm3 = w & 1, wn3 = w >> 1;
        const int rot3 = (bid * 3) & 15;
        f32x4 acc = {0.f, 0.f, 0.f, 0.f};
        const short8* W3f = (const short8*)w3pk + (size_t)(wn3 * 16) * 64 + l;
#pragma unroll
        for (int i = 0; i < 16; ++i) {
            int ks = (i + rot3) & 15;
            short8 ah = *(const short8*)(h2b + act_addr(wm3 * 16 + lr, ks * 64 + g * 16));
            acc = __builtin_amdgcn_mfma_f32_16x16x32_bf16(ah, W3f[ks * 64], acc, 0, 0, 0);
        }
        int c = wn3 * 16 + lr;
        float b3v = b3[c];
#pragma unroll
        for (int r = 0; r < 4; ++r)
            out[(size_t)(s0 + wm3 * 16 + g * 4 + r) * DIM + c] = acc[r] + b3v;
    }
    __syncthreads();   // wred complete
    if (tid < MB) {
        float d = 0.f;
#pragma unroll
        for (int ww = 0; ww < 8; ++ww) d += wred[ww][tid];
        out[(size_t)BATCH * DIM + s0 + tid] = -d;
    }
}

extern "C" void kernel_launch(void* const* d_in, const int* in_sizes, int n_in,
                              void* d_out, int out_size, void* d_ws, size_t ws_size,
                              hipStream_t stream) {
    const float* t  = (const float*)d_in[0];
    const float* x  = (const float*)d_in[1];
    const float* W1 = (const float*)d_in[2];
    const float* b1 = (const float*)d_in[3];
    const float* W2 = (const float*)d_in[4];
    const float* b2 = (const float*)d_in[5];
    const float* W3 = (const float*)d_in[6];
    const float* b3 = (const float*)d_in[7];
    float* out = (float*)d_out;

    char* ws = (char*)d_ws;
    unsigned short* w2pk = (unsigned short*)ws;                            // 512 KB
    unsigned short* ppk  = (unsigned short*)(ws + (512 << 10));            // 512 KB
    unsigned short* w3pk = (unsigned short*)(ws + (1 << 20));              // 64 KB
    unsigned short* w1pk = (unsigned short*)(ws + (1 << 20) + (64 << 10)); // 64 KB
    float*          c1   = (float*)(ws + (1 << 20) + (128 << 10));         // 2 KB

    prep<<<290, 256, 0, stream>>>(t, W1, b1, W2, W3, w2pk, ppk, w3pk, w1pk, c1);
    fused_main<<<BATCH / MB, NTHR, 0, stream>>>(x, c1, b2, b3, w1pk, w2pk, ppk, w3pk, out);
}